// Round 7
// baseline (1267.960 us; speedup 1.0000x reference)
//
#include <hip/hip_runtime.h>
#include <hip/hip_bf16.h>
#include <stdint.h>

#define E_N 16
#define TOPK 4
#define DD 2560
#define FF 1664
#define FSS 3328
#define TT 2048

#define BK 32

typedef __attribute__((ext_vector_type(8))) __bf16 bf16x8;
typedef __attribute__((ext_vector_type(4))) float f32x4;

__device__ __forceinline__ unsigned short f2bf(float f) {
  return __builtin_bit_cast(unsigned short, (__bf16)f);
}
__device__ __forceinline__ float bf2f(unsigned short u) {
  return __builtin_bit_cast(float, (unsigned int)u << 16);
}
__device__ __forceinline__ unsigned int pk2(float a, float b) {
  return (unsigned int)f2bf(a) | ((unsigned int)f2bf(b) << 16);
}

#define GLOAD16(g, l)                                                          \
  __builtin_amdgcn_global_load_lds(                                            \
      (const __attribute__((address_space(1))) void*)(g),                      \
      (__attribute__((address_space(3))) void*)(l), 16, 0, 0)

#define SBAR() __builtin_amdgcn_s_barrier()
#define SCHED0() __builtin_amdgcn_sched_barrier(0)
#define VMW(N) asm volatile("s_waitcnt vmcnt(" #N ")" ::: "memory")

// swizzled block decompose: XCD-chunked bijective remap (requires nwg%8==0)
__device__ __forceinline__ void swz_block(int& bm, int& bn, int& bz) {
  int gx = gridDim.x, gy = gridDim.y;
  int nwg = gx * gy * gridDim.z;
  int flat = blockIdx.x + gx * (blockIdx.y + gy * blockIdx.z);
  if ((nwg & 7) == 0) flat = (flat & 7) * (nwg >> 3) + (flat >> 3);
  bm = flat % gx;
  int rest = flat / gx;
  bn = rest % gy;
  bz = rest / gy;
}

// ---------------- X -> bf16 ----------------
__global__ __launch_bounds__(256) void cvt_bf16_kernel(const float* __restrict__ in,
                                                       unsigned short* __restrict__ out) {
  size_t i = ((size_t)blockIdx.x * 256 + threadIdx.x) * 4;
  float4 v = *reinterpret_cast<const float4*>(in + i);
  ushort4 o;
  o.x = f2bf(v.x); o.y = f2bf(v.y); o.z = f2bf(v.z); o.w = f2bf(v.w);
  *reinterpret_cast<ushort4*>(out + i) = o;
}

// ---------------- weight transpose+convert: [K][N] f32 -> [N][K] bf16 ----------------
__global__ __launch_bounds__(256) void tcvt_kernel(const float* __restrict__ in,
                                                   unsigned short* __restrict__ out,
                                                   int K, int N) {
  __shared__ float lds[64 * 65];
  int z = blockIdx.z;
  in += (size_t)z * K * N;
  out += (size_t)z * K * N;
  int k0 = blockIdx.x * 64, n0 = blockIdx.y * 64;
  int t = threadIdx.x;
#pragma unroll
  for (int j = 0; j < 4; ++j) {
    int idx = j * 256 + t;
    int r = idx >> 4, c = (idx & 15) * 4;
    float4 v = *reinterpret_cast<const float4*>(in + (size_t)(k0 + r) * N + n0 + c);
    lds[r * 65 + c] = v.x;
    lds[r * 65 + c + 1] = v.y;
    lds[r * 65 + c + 2] = v.z;
    lds[r * 65 + c + 3] = v.w;
  }
  __syncthreads();
#pragma unroll
  for (int j = 0; j < 2; ++j) {
    int idx = j * 256 + t;
    int n = idx >> 3, kg = (idx & 7) * 8;
    float a0 = lds[(kg + 0) * 65 + n], a1 = lds[(kg + 1) * 65 + n];
    float a2 = lds[(kg + 2) * 65 + n], a3 = lds[(kg + 3) * 65 + n];
    float a4 = lds[(kg + 4) * 65 + n], a5 = lds[(kg + 5) * 65 + n];
    float a6 = lds[(kg + 6) * 65 + n], a7 = lds[(kg + 7) * 65 + n];
    uint4 o{pk2(a0, a1), pk2(a2, a3), pk2(a4, a5), pk2(a6, a7)};
    *reinterpret_cast<uint4*>(out + (size_t)(n0 + n) * K + k0 + kg) = o;
  }
}

// ---------------- Router ----------------
__global__ __launch_bounds__(256) void router_kernel(const float* __restrict__ x,
                                                     const float* __restrict__ rw,
                                                     int* __restrict__ cnt,
                                                     int* __restrict__ list,
                                                     float* __restrict__ tw) {
  int t = blockIdx.x;
  const float* xr = x + (size_t)t * DD;
  __shared__ float logits[E_N];
  int lane = threadIdx.x & 63, wid = threadIdx.x >> 6;
  for (int ee = 0; ee < 4; ++ee) {
    int e = wid * 4 + ee;
    const float* wr = rw + (size_t)e * DD;
    float p = 0.f;
    for (int d = lane; d < DD; d += 64) p += xr[d] * wr[d];
#pragma unroll
    for (int off = 32; off > 0; off >>= 1) p += __shfl_down(p, off);
    if (lane == 0) logits[e] = p;
  }
  __syncthreads();
  if (threadIdx.x == 0) {
    float mx = -1e30f;
    for (int e = 0; e < E_N; ++e) mx = fmaxf(mx, logits[e]);
    float pe[E_N];
    for (int e = 0; e < E_N; ++e) pe[e] = __expf(logits[e] - mx);
    int idx[TOPK]; float val[TOPK]; float s4 = 0.f;
    unsigned used = 0;
    for (int k = 0; k < TOPK; ++k) {
      int bi = 0; float bv = -1.f;
      for (int e = 0; e < E_N; ++e)
        if (!((used >> e) & 1) && pe[e] > bv) { bv = pe[e]; bi = e; }
      used |= 1u << bi; idx[k] = bi; val[k] = bv; s4 += bv;
    }
    float inv = 1.f / s4;
    for (int k = 0; k < TOPK; ++k) {
      int e2 = idx[k];
      int pos = atomicAdd(&cnt[e2], 1);
      list[e2 * TT + pos] = t * 4 + k;
      tw[t * 4 + k] = val[k] * inv;
    }
  }
}

// ---------------- generic 256x256 grouped GEMM ----------------
// MODE 0: A = activations (gather token = code>>2 when listed), bf16 raw out at row=code.
// MODE 1: A = H (gather row = code), f32 out at row=code scaled by tw[code].
// 512 threads, 8 waves (2m x 4n), BK=32, ring-4 LDS (4 x 32KB = 128KB), 1 barrier/iter.
template <int MODE>
__global__ __launch_bounds__(512, 2) void g1_kernel(
    const unsigned short* __restrict__ Ab,   // bf16 [rows][Ktot]
    const unsigned short* __restrict__ WT,   // [E][Ntot][Ktot] bf16
    void* __restrict__ Out,
    const int* __restrict__ list, const int* __restrict__ cnt,
    const float* __restrict__ tw,
    int Ktot, int Ntot, int Mfixed) {
  int bm, bn, e;
  swz_block(bm, bn, e);
  int M = cnt ? cnt[e] : Mfixed;
  int m0 = bm * 256;
  if (m0 >= M) return;
  int n0 = bn * 256;
  const unsigned short* B0 = WT + (size_t)e * Ktot * Ntot;
  const int* lst = list ? (list + e * TT) : nullptr;

  __shared__ __align__(16) unsigned short lds[4][16384];  // 128KB: A 16KB | B 16KB per buf

  int tid = threadIdx.x, lane = tid & 63, w = tid >> 6;
  int wm = w >> 2, wn = w & 3;

  // staging pointers: 2 A-chunks + 2 B-chunks per thread per tile
  const unsigned short* pA[2];
  const unsigned short* pB[2];
#pragma unroll
  for (int j = 0; j < 2; ++j) {
    int idx = j * 512 + tid;
    int row = idx >> 2, c = idx & 3;
    int cs = c ^ ((row >> 1) & 3);
    int ar = min(m0 + row, M - 1);
    int code = lst ? lst[ar] : ar;
    int arow = (MODE == 0) ? (lst ? (code >> 2) : code) : code;
    pA[j] = Ab + (size_t)arow * Ktot + cs * 8;
    int br = min(n0 + row, Ntot - 1);
    pB[j] = B0 + (size_t)br * Ktot + cs * 8;
  }

  auto issue = [&](int kt, int buf) {
    int koff = kt * BK;
    unsigned short* d = &lds[buf][0];
#pragma unroll
    for (int j = 0; j < 2; ++j)
      GLOAD16(pA[j] + koff, d + (j * 512 + tid) * 8);
#pragma unroll
    for (int j = 0; j < 2; ++j)
      GLOAD16(pB[j] + koff, d + 8192 + (j * 512 + tid) * 8);
  };

  int cg = lane >> 4;
  int aoff[8], boff[4];
#pragma unroll
  for (int mf = 0; mf < 8; ++mf) {
    int r = wm * 128 + mf * 16 + (lane & 15);
    aoff[mf] = r * 32 + ((cg ^ ((r >> 1) & 3)) * 8);
  }
#pragma unroll
  for (int nf = 0; nf < 4; ++nf) {
    int rb = wn * 64 + nf * 16 + (lane & 15);
    boff[nf] = 8192 + rb * 32 + ((cg ^ ((rb >> 1) & 3)) * 8);
  }

  f32x4 acc[8][4] = {};

  auto compute = [&](int buf) {
    const unsigned short* L = &lds[buf][0];
    bf16x8 a[8], b[4];
#pragma unroll
    for (int mf = 0; mf < 8; ++mf)
      a[mf] = __builtin_bit_cast(bf16x8, *reinterpret_cast<const uint4*>(L + aoff[mf]));
#pragma unroll
    for (int nf = 0; nf < 4; ++nf)
      b[nf] = __builtin_bit_cast(bf16x8, *reinterpret_cast<const uint4*>(L + boff[nf]));
    __builtin_amdgcn_s_setprio(1);
#pragma unroll
    for (int mf = 0; mf < 8; ++mf)
#pragma unroll
      for (int nf = 0; nf < 4; ++nf)
        acc[mf][nf] = __builtin_amdgcn_mfma_f32_16x16x32_bf16(a[mf], b[nf], acc[mf][nf], 0, 0, 0);
    __builtin_amdgcn_s_setprio(0);
  };

  int nk = Ktot / BK;
  issue(0, 0);
  issue(1, 1);
  issue(2, 2);
  // single barrier per iter (ring-4): passing SBAR at iter kt proves all waves
  // finished compute(kt-1); buf (kt+3)%4 == (kt-1)%4 is then free to overwrite.
  for (int kt = 0; kt < nk; ++kt) {
    int rem = nk - 1 - kt;
    if (rem >= 2) { VMW(8); }
    else if (rem == 1) { VMW(4); }
    else { VMW(0); }
    SCHED0();
    SBAR(); SCHED0();
    if (rem >= 3) { issue(kt + 3, (kt + 3) & 3); SCHED0(); }
    compute(kt & 3);
    SCHED0();
  }

  // epilogue
#pragma unroll
  for (int mf = 0; mf < 8; ++mf) {
#pragma unroll
    for (int q = 0; q < 4; ++q) {
      int lr = wm * 128 + mf * 16 + (lane >> 4) * 4 + q;
      int grow = m0 + lr;
      if (grow < M) {
        int code = lst ? lst[grow] : grow;
        int colb = n0 + wn * 64 + (lane & 15);
        if (MODE == 0) {
          unsigned short* Op = (unsigned short*)Out + (size_t)code * Ntot + colb;
#pragma unroll
          for (int nf = 0; nf < 4; ++nf)
            if (colb + nf * 16 < Ntot) Op[nf * 16] = f2bf(acc[mf][nf][q]);
        } else {
          float scale = tw ? tw[code] : 1.f;
          float* Op = (float*)Out + (size_t)code * Ntot + colb;
#pragma unroll
          for (int nf = 0; nf < 4; ++nf)
            if (colb + nf * 16 < Ntot) Op[nf * 16] = acc[mf][nf][q] * scale;
        }
      }
    }
  }
}

// ---------------- h = silu(g) * u, elementwise in-place on u ----------------
__global__ __launch_bounds__(256) void h_kernel(const unsigned short* __restrict__ g,
                                                unsigned short* __restrict__ u) {
  size_t i = ((size_t)blockIdx.x * 256 + threadIdx.x) * 8;
  uint4 gv = *reinterpret_cast<const uint4*>(g + i);
  uint4 uv = *reinterpret_cast<const uint4*>(u + i);
  const unsigned int* gw = reinterpret_cast<const unsigned int*>(&gv);
  const unsigned int* uw = reinterpret_cast<const unsigned int*>(&uv);
  uint4 ov;
  unsigned int* ow = reinterpret_cast<unsigned int*>(&ov);
#pragma unroll
  for (int j = 0; j < 4; ++j) {
    float g0 = bf2f((unsigned short)(gw[j] & 0xffff));
    float g1 = bf2f((unsigned short)(gw[j] >> 16));
    float u0 = bf2f((unsigned short)(uw[j] & 0xffff));
    float u1 = bf2f((unsigned short)(uw[j] >> 16));
    float h0 = (g0 / (1.f + __expf(-g0))) * u0;
    float h1 = (g1 / (1.f + __expf(-g1))) * u1;
    ow[j] = pk2(h0, h1);
  }
  *reinterpret_cast<uint4*>(u + i) = ov;
}

// ---------------- combine ----------------
__global__ __launch_bounds__(256) void combine_kernel(const float* __restrict__ Y,
                                                      const float* __restrict__ Ys,
                                                      float* __restrict__ out) {
  size_t i = ((size_t)blockIdx.x * 256 + threadIdx.x) * 4;
  size_t t = i / DD;
  int d = (int)(i % DD);
  float4 a = *reinterpret_cast<const float4*>(Ys + i);
#pragma unroll
  for (int k = 0; k < 4; ++k) {
    float4 v = *reinterpret_cast<const float4*>(Y + (t * 4 + k) * (size_t)DD + d);
    a.x += v.x; a.y += v.y; a.z += v.z; a.w += v.w;
  }
  *reinterpret_cast<float4*>(out + i) = a;
}

extern "C" void kernel_launch(void* const* d_in, const int* in_sizes, int n_in,
                              void* d_out, int out_size, void* d_ws, size_t ws_size,
                              hipStream_t stream) {
  const float* x  = (const float*)d_in[0];
  const float* rw = (const float*)d_in[1];
  const float* wg = (const float*)d_in[2];
  const float* wu = (const float*)d_in[3];
  const float* wd = (const float*)d_in[4];
  const float* sg = (const float*)d_in[5];
  const float* su = (const float*)d_in[6];
  const float* sd = (const float*)d_in[7];
  float* out = (float*)d_out;

  char* ws = (char*)d_ws;
  size_t off = 0;
  auto alloc = [&](size_t bytes) {
    off = (off + 255) & ~(size_t)255;
    void* p = ws + off;
    off += bytes;
    return p;
  };
  unsigned short* W1 = (unsigned short*)alloc((size_t)E_N * FF * DD * 2);   // 136 MB
  unsigned short* W2 = (unsigned short*)alloc((size_t)E_N * FF * DD * 2);   // 136 MB
  unsigned short* W3 = (unsigned short*)alloc((size_t)FSS * DD * 2);        // 17 MB
  unsigned short* W4 = (unsigned short*)alloc((size_t)FSS * DD * 2);        // 17 MB
  unsigned short* Xb = (unsigned short*)alloc((size_t)TT * DD * 2);
  unsigned short* Gx = (unsigned short*)alloc((size_t)4 * TT * FF * 2);     // 27 MB
  unsigned short* Hx = (unsigned short*)alloc((size_t)4 * TT * FF * 2);     // 27 MB (U then H in-place)
  unsigned short* Gs = (unsigned short*)alloc((size_t)TT * FSS * 2);        // 13.6 MB
  unsigned short* Hs = (unsigned short*)alloc((size_t)TT * FSS * 2);
  float* Y  = (float*)alloc((size_t)4 * TT * DD * 4);
  float* Ys = (float*)alloc((size_t)TT * DD * 4);
  float* tw = (float*)alloc((size_t)4 * TT * 4);
  int* cnt  = (int*)alloc(E_N * 4);
  int* list = (int*)alloc((size_t)E_N * TT * 4);
  (void)ws_size; (void)in_sizes; (void)n_in; (void)out_size;

  hipMemsetAsync(cnt, 0, E_N * 4, stream);
  cvt_bf16_kernel<<<TT * DD / 4 / 256, 256, 0, stream>>>(x, Xb);
  router_kernel<<<TT, 256, 0, stream>>>(x, rw, cnt, list, tw);

  // --- gate/up weight transposes: [D][F(S)] -> [F(S)][D] bf16 ---
  tcvt_kernel<<<dim3(DD / 64, FF / 64, E_N), 256, 0, stream>>>(wg, W1, DD, FF);
  tcvt_kernel<<<dim3(DD / 64, FF / 64, E_N), 256, 0, stream>>>(wu, W2, DD, FF);
  tcvt_kernel<<<dim3(DD / 64, FSS / 64, 1), 256, 0, stream>>>(sg, W3, DD, FSS);
  tcvt_kernel<<<dim3(DD / 64, FSS / 64, 1), 256, 0, stream>>>(su, W4, DD, FSS);

  // --- expert gate & up passes (256x256), then silu fuse ---
  g1_kernel<0><<<dim3(TT * 4 / 256, (FF + 255) / 256, E_N), 512, 0, stream>>>(
      Xb, W1, Gx, list, cnt, nullptr, DD, FF, 0);
  g1_kernel<0><<<dim3(TT * 4 / 256, (FF + 255) / 256, E_N), 512, 0, stream>>>(
      Xb, W2, Hx, list, cnt, nullptr, DD, FF, 0);
  h_kernel<<<(size_t)4 * TT * FF / 8 / 256, 256, 0, stream>>>(Gx, Hx);

  // --- shared gate & up passes ---
  g1_kernel<0><<<dim3(TT / 256, FSS / 256, 1), 512, 0, stream>>>(
      Xb, W3, Gs, nullptr, nullptr, nullptr, DD, FSS, TT);
  g1_kernel<0><<<dim3(TT / 256, FSS / 256, 1), 512, 0, stream>>>(
      Xb, W4, Hs, nullptr, nullptr, nullptr, DD, FSS, TT);
  h_kernel<<<(size_t)TT * FSS / 8 / 256, 256, 0, stream>>>(Gs, Hs);

  // --- down weight transposes: [F(S)][D] -> [D][F(S)] bf16 (reuse W1/W2) ---
  tcvt_kernel<<<dim3(FF / 64, DD / 64, E_N), 256, 0, stream>>>(wd, W1, FF, DD);
  tcvt_kernel<<<dim3(FSS / 64, DD / 64, 1), 256, 0, stream>>>(sd, W2, FSS, DD);

  // --- down GEMMs (256x256) ---
  g1_kernel<1><<<dim3(TT * 4 / 256, DD / 256, E_N), 512, 0, stream>>>(
      Hx, W1, Y, list, cnt, tw, FF, DD, 0);
  g1_kernel<1><<<dim3(TT / 256, DD / 256, 1), 512, 0, stream>>>(
      Hs, W2, Ys, nullptr, nullptr, nullptr, FSS, DD, TT);

  combine_kernel<<<TT * DD / 4 / 256, 256, 0, stream>>>(Y, Ys, out);
}

// Round 8
// 1195.025 us; speedup vs baseline: 1.0610x; 1.0610x over previous
//
#include <hip/hip_runtime.h>
#include <hip/hip_bf16.h>
#include <stdint.h>

#define E_N 16
#define TOPK 4
#define DD 2560
#define FF 1664
#define FSS 3328
#define TT 2048

typedef __attribute__((ext_vector_type(8))) __bf16 bf16x8;
typedef __attribute__((ext_vector_type(4))) float f32x4;

__device__ __forceinline__ unsigned short f2bf(float f) {
  return __builtin_bit_cast(unsigned short, (__bf16)f);
}
__device__ __forceinline__ float bf2f(unsigned short u) {
  return __builtin_bit_cast(float, (unsigned int)u << 16);
}
__device__ __forceinline__ unsigned int pk2(float a, float b) {
  return (unsigned int)f2bf(a) | ((unsigned int)f2bf(b) << 16);
}

#define GLOAD16(g, l)                                                          \
  __builtin_amdgcn_global_load_lds(                                            \
      (const __attribute__((address_space(1))) void*)(g),                      \
      (__attribute__((address_space(3))) void*)(l), 16, 0, 0)

// swizzled block decompose: XCD-chunked bijective remap (requires nwg%8==0)
__device__ __forceinline__ void swz_block(int& bm, int& bn, int& bz) {
  int gx = gridDim.x, gy = gridDim.y;
  int nwg = gx * gy * gridDim.z;
  int flat = blockIdx.x + gx * (blockIdx.y + gy * blockIdx.z);
  if ((nwg & 7) == 0) flat = (flat & 7) * (nwg >> 3) + (flat >> 3);
  bm = flat % gx;
  int rest = flat / gx;
  bn = rest % gy;
  bz = rest / gy;
}

// ---------------- X -> bf16 ----------------
__global__ __launch_bounds__(256) void cvt_bf16_kernel(const float* __restrict__ in,
                                                       unsigned short* __restrict__ out) {
  size_t i = ((size_t)blockIdx.x * 256 + threadIdx.x) * 4;
  float4 v = *reinterpret_cast<const float4*>(in + i);
  ushort4 o;
  o.x = f2bf(v.x); o.y = f2bf(v.y); o.z = f2bf(v.z); o.w = f2bf(v.w);
  *reinterpret_cast<ushort4*>(out + i) = o;
}

// ---------------- weight transpose+convert: [K][N] f32 -> [N][K] bf16 ----------------
__global__ __launch_bounds__(256) void tcvt_kernel(const float* __restrict__ in,
                                                   unsigned short* __restrict__ out,
                                                   int K, int N) {
  __shared__ float lds[64 * 65];
  int z = blockIdx.z;
  in += (size_t)z * K * N;
  out += (size_t)z * K * N;
  int k0 = blockIdx.x * 64, n0 = blockIdx.y * 64;
  int t = threadIdx.x;
#pragma unroll
  for (int j = 0; j < 4; ++j) {
    int idx = j * 256 + t;
    int r = idx >> 4, c = (idx & 15) * 4;
    float4 v = *reinterpret_cast<const float4*>(in + (size_t)(k0 + r) * N + n0 + c);
    lds[r * 65 + c] = v.x;
    lds[r * 65 + c + 1] = v.y;
    lds[r * 65 + c + 2] = v.z;
    lds[r * 65 + c + 3] = v.w;
  }
  __syncthreads();
#pragma unroll
  for (int j = 0; j < 2; ++j) {
    int idx = j * 256 + t;
    int n = idx >> 3, kg = (idx & 7) * 8;
    float a0 = lds[(kg + 0) * 65 + n], a1 = lds[(kg + 1) * 65 + n];
    float a2 = lds[(kg + 2) * 65 + n], a3 = lds[(kg + 3) * 65 + n];
    float a4 = lds[(kg + 4) * 65 + n], a5 = lds[(kg + 5) * 65 + n];
    float a6 = lds[(kg + 6) * 65 + n], a7 = lds[(kg + 7) * 65 + n];
    uint4 o{pk2(a0, a1), pk2(a2, a3), pk2(a4, a5), pk2(a6, a7)};
    *reinterpret_cast<uint4*>(out + (size_t)(n0 + n) * K + k0 + kg) = o;
  }
}

// ---------------- Router ----------------
__global__ __launch_bounds__(256) void router_kernel(const float* __restrict__ x,
                                                     const float* __restrict__ rw,
                                                     int* __restrict__ cnt,
                                                     int* __restrict__ list,
                                                     float* __restrict__ tw) {
  int t = blockIdx.x;
  const float* xr = x + (size_t)t * DD;
  __shared__ float logits[E_N];
  int lane = threadIdx.x & 63, wid = threadIdx.x >> 6;
  for (int ee = 0; ee < 4; ++ee) {
    int e = wid * 4 + ee;
    const float* wr = rw + (size_t)e * DD;
    float p = 0.f;
    for (int d = lane; d < DD; d += 64) p += xr[d] * wr[d];
#pragma unroll
    for (int off = 32; off > 0; off >>= 1) p += __shfl_down(p, off);
    if (lane == 0) logits[e] = p;
  }
  __syncthreads();
  if (threadIdx.x == 0) {
    float mx = -1e30f;
    for (int e = 0; e < E_N; ++e) mx = fmaxf(mx, logits[e]);
    float pe[E_N];
    for (int e = 0; e < E_N; ++e) pe[e] = __expf(logits[e] - mx);
    int idx[TOPK]; float val[TOPK]; float s4 = 0.f;
    unsigned used = 0;
    for (int k = 0; k < TOPK; ++k) {
      int bi = 0; float bv = -1.f;
      for (int e = 0; e < E_N; ++e)
        if (!((used >> e) & 1) && pe[e] > bv) { bv = pe[e]; bi = e; }
      used |= 1u << bi; idx[k] = bi; val[k] = bv; s4 += bv;
    }
    float inv = 1.f / s4;
    for (int k = 0; k < TOPK; ++k) {
      int e2 = idx[k];
      int pos = atomicAdd(&cnt[e2], 1);
      list[e2 * TT + pos] = t * 4 + k;
      tw[t * 4 + k] = val[k] * inv;
    }
  }
}

// ---------------- m97-replica GEMM body ----------------
// 128x128 tile, BK=64, single 32KB LDS buffer, 4 waves, aiming 3 blocks/CU.
// MODE 0: bf16 raw store at row=code (SHIFT=1: gather token=code>>2).
// MODE 1: f32 store at row=code scaled by tw[code] (SHIFT=0: gather row=code).
template <int MODE, int SHIFT>
__device__ __forceinline__ void gemm_body(
    const unsigned short* __restrict__ A0, const unsigned short* __restrict__ W0,
    void* __restrict__ O0, const int* lst, const float* __restrict__ tw,
    int M, int Kt, int Nt, int m0, int n0) {
  __shared__ __align__(16) unsigned short ldsA[8192];
  __shared__ __align__(16) unsigned short ldsB[8192];

  int tid = threadIdx.x, lane = tid & 63, w = tid >> 6;

  // staging pointers: 4 A-rows + 4 B-rows per thread, 128B rows (64 bf16, 8 chunks)
  // source pre-swizzle: chunk c -> c ^ (row & 7); LDS dest stays linear.
  const unsigned short* pA[4];
  const unsigned short* pB[4];
#pragma unroll
  for (int j = 0; j < 4; ++j) {
    int row = j * 32 + (tid >> 3);
    int cs = (tid & 7) ^ (row & 7);
    int ar = min(m0 + row, M - 1);
    int code = lst ? lst[ar] : ar;
    int arow = SHIFT ? (lst ? (code >> 2) : code) : code;
    pA[j] = A0 + (size_t)arow * Kt + cs * 8;
    pB[j] = W0 + (size_t)(n0 + j * 32 + (tid >> 3)) * Kt + cs * 8;
  }

  auto issue = [&](int kt) {
    int koff = kt * 64;
#pragma unroll
    for (int j = 0; j < 4; ++j) {
      GLOAD16(pA[j] + koff, ldsA + j * 2048 + tid * 8);
      GLOAD16(pB[j] + koff, ldsB + j * 2048 + tid * 8);
    }
  };

  int wr = (w >> 1) * 64, wc = (w & 1) * 64;
  int aoff[4][2], boff[4][2];
#pragma unroll
  for (int m = 0; m < 4; ++m) {
    int r = wr + m * 16 + (lane & 15);
    int rb = wc + m * 16 + (lane & 15);
#pragma unroll
    for (int kh = 0; kh < 2; ++kh) {
      int cg = kh * 4 + (lane >> 4);
      aoff[m][kh] = r * 64 + ((cg ^ (r & 7)) * 8);
      boff[m][kh] = rb * 64 + ((cg ^ (rb & 7)) * 8);
    }
  }

  f32x4 acc[4][4] = {};

  int nk = Kt / 64;
  issue(0);
  for (int kt = 0; kt < nk; ++kt) {
    __syncthreads();  // compiler drains vmcnt(0): tile kt fully in LDS
#pragma unroll
    for (int kh = 0; kh < 2; ++kh) {
      bf16x8 a[4], b[4];
#pragma unroll
      for (int m = 0; m < 4; ++m)
        a[m] = __builtin_bit_cast(bf16x8, *reinterpret_cast<const uint4*>(ldsA + aoff[m][kh]));
#pragma unroll
      for (int n = 0; n < 4; ++n)
        b[n] = __builtin_bit_cast(bf16x8, *reinterpret_cast<const uint4*>(ldsB + boff[n][kh]));
      __builtin_amdgcn_s_setprio(1);
#pragma unroll
      for (int m = 0; m < 4; ++m)
#pragma unroll
        for (int n = 0; n < 4; ++n)
          acc[m][n] = __builtin_amdgcn_mfma_f32_16x16x32_bf16(a[m], b[n], acc[m][n], 0, 0, 0);
      __builtin_amdgcn_s_setprio(0);
    }
    __syncthreads();  // all waves done reading the buffer
    if (kt + 1 < nk) issue(kt + 1);
  }

  // epilogue (C/D layout: col=lane&15, row=(lane>>4)*4+q per 16x16 frag)
#pragma unroll
  for (int m = 0; m < 4; ++m) {
#pragma unroll
    for (int q = 0; q < 4; ++q) {
      int lr = wr + m * 16 + (lane >> 4) * 4 + q;
      int grow = m0 + lr;
      if (grow < M) {
        int code = lst ? lst[grow] : grow;
        int col = n0 + wc + (lane & 15);
        if (MODE == 0) {
          unsigned short* Op = (unsigned short*)O0 + (size_t)code * Nt + col;
#pragma unroll
          for (int n = 0; n < 4; ++n) Op[n * 16] = f2bf(acc[m][n][q]);
        } else {
          float scale = tw ? tw[code] : 1.f;
          float* Op = (float*)O0 + (size_t)code * Nt + col;
#pragma unroll
          for (int n = 0; n < 4; ++n) Op[n * 16] = acc[m][n][q] * scale;
        }
      }
    }
  }
}

// ---------------- mega gate+up launch: z=0..15 expert-G, 16 shared-G,
//                  17..32 expert-U, 33 shared-U ----------------
__global__ __launch_bounds__(256, 3) void gu2_kernel(
    const unsigned short* __restrict__ Xb,
    const unsigned short* __restrict__ WgT, const unsigned short* __restrict__ WuT,
    const unsigned short* __restrict__ SgT, const unsigned short* __restrict__ SuT,
    unsigned short* __restrict__ Gx, unsigned short* __restrict__ Ux,
    unsigned short* __restrict__ Gs, unsigned short* __restrict__ Us,
    const int* __restrict__ list, const int* __restrict__ cnt) {
  int bm, bn, z;
  swz_block(bm, bn, z);
  bool up = z >= 17;
  int ze = up ? z - 17 : z;
  const unsigned short* W0;
  unsigned short* O0;
  const int* lst = nullptr;
  int M, Nt;
  if (ze < E_N) {
    M = cnt[ze];
    lst = list + ze * TT;
    Nt = FF;
    W0 = (up ? WuT : WgT) + (size_t)ze * DD * FF;
    O0 = up ? Ux : Gx;
  } else {
    M = TT;
    Nt = FSS;
    W0 = up ? SuT : SgT;
    O0 = up ? Us : Gs;
  }
  int m0 = bm * 128, n0 = bn * 128;
  if (m0 >= M || n0 >= Nt) return;
  gemm_body<0, 1>(Xb, W0, O0, lst, nullptr, M, DD, Nt, m0, n0);
}

// ---------------- mega down launch: z=0..15 expert, 16 shared ----------------
__global__ __launch_bounds__(256, 3) void dn2_kernel(
    const unsigned short* __restrict__ Hx, const unsigned short* __restrict__ Hs,
    const unsigned short* __restrict__ WdT, const unsigned short* __restrict__ SdT,
    float* __restrict__ Y, float* __restrict__ Ys,
    const int* __restrict__ list, const int* __restrict__ cnt,
    const float* __restrict__ tw) {
  int bm, bn, z;
  swz_block(bm, bn, z);
  const unsigned short* A0;
  const unsigned short* W0;
  float* O0;
  const int* lst = nullptr;
  const float* sc = nullptr;
  int M, Kt;
  if (z < E_N) {
    M = cnt[z];
    lst = list + z * TT;
    Kt = FF;
    A0 = Hx;
    W0 = WdT + (size_t)z * FF * DD;
    O0 = Y;
    sc = tw;
  } else {
    M = TT;
    Kt = FSS;
    A0 = Hs;
    W0 = SdT;
    O0 = Ys;
  }
  int m0 = bm * 128, n0 = bn * 128;
  if (m0 >= M) return;
  gemm_body<1, 0>(A0, W0, O0, lst, sc, M, Kt, DD, m0, n0);
}

// ---------------- h = silu(g) * u, elementwise in-place on u ----------------
__global__ __launch_bounds__(256) void h_kernel(const unsigned short* __restrict__ g,
                                                unsigned short* __restrict__ u) {
  size_t i = ((size_t)blockIdx.x * 256 + threadIdx.x) * 8;
  uint4 gv = *reinterpret_cast<const uint4*>(g + i);
  uint4 uv = *reinterpret_cast<const uint4*>(u + i);
  const unsigned int* gw = reinterpret_cast<const unsigned int*>(&gv);
  const unsigned int* uw = reinterpret_cast<const unsigned int*>(&uv);
  uint4 ov;
  unsigned int* ow = reinterpret_cast<unsigned int*>(&ov);
#pragma unroll
  for (int j = 0; j < 4; ++j) {
    float g0 = bf2f((unsigned short)(gw[j] & 0xffff));
    float g1 = bf2f((unsigned short)(gw[j] >> 16));
    float u0 = bf2f((unsigned short)(uw[j] & 0xffff));
    float u1 = bf2f((unsigned short)(uw[j] >> 16));
    float h0 = (g0 / (1.f + __expf(-g0))) * u0;
    float h1 = (g1 / (1.f + __expf(-g1))) * u1;
    ow[j] = pk2(h0, h1);
  }
  *reinterpret_cast<uint4*>(u + i) = ov;
}

// ---------------- combine ----------------
__global__ __launch_bounds__(256) void combine_kernel(const float* __restrict__ Y,
                                                      const float* __restrict__ Ys,
                                                      float* __restrict__ out) {
  size_t i = ((size_t)blockIdx.x * 256 + threadIdx.x) * 4;
  size_t t = i / DD;
  int d = (int)(i % DD);
  float4 a = *reinterpret_cast<const float4*>(Ys + i);
#pragma unroll
  for (int k = 0; k < 4; ++k) {
    float4 v = *reinterpret_cast<const float4*>(Y + (t * 4 + k) * (size_t)DD + d);
    a.x += v.x; a.y += v.y; a.z += v.z; a.w += v.w;
  }
  *reinterpret_cast<float4*>(out + i) = a;
}

extern "C" void kernel_launch(void* const* d_in, const int* in_sizes, int n_in,
                              void* d_out, int out_size, void* d_ws, size_t ws_size,
                              hipStream_t stream) {
  const float* x  = (const float*)d_in[0];
  const float* rw = (const float*)d_in[1];
  const float* wg = (const float*)d_in[2];
  const float* wu = (const float*)d_in[3];
  const float* wd = (const float*)d_in[4];
  const float* sg = (const float*)d_in[5];
  const float* su = (const float*)d_in[6];
  const float* sd = (const float*)d_in[7];
  float* out = (float*)d_out;

  char* ws = (char*)d_ws;
  size_t off = 0;
  auto alloc = [&](size_t bytes) {
    off = (off + 255) & ~(size_t)255;
    void* p = ws + off;
    off += bytes;
    return p;
  };
  unsigned short* W1 = (unsigned short*)alloc((size_t)E_N * FF * DD * 2);   // 136 MB
  unsigned short* W2 = (unsigned short*)alloc((size_t)E_N * FF * DD * 2);   // 136 MB
  unsigned short* W3 = (unsigned short*)alloc((size_t)FSS * DD * 2);        // 17 MB
  unsigned short* W4 = (unsigned short*)alloc((size_t)FSS * DD * 2);        // 17 MB
  unsigned short* Xb = (unsigned short*)alloc((size_t)TT * DD * 2);
  unsigned short* Gx = (unsigned short*)alloc((size_t)4 * TT * FF * 2);     // raw expert G
  unsigned short* Hx = (unsigned short*)alloc((size_t)4 * TT * FF * 2);     // raw U -> H
  unsigned short* Gs = (unsigned short*)alloc((size_t)TT * FSS * 2);
  unsigned short* Hs = (unsigned short*)alloc((size_t)TT * FSS * 2);
  float* Y  = (float*)alloc((size_t)4 * TT * DD * 4);
  float* Ys = (float*)alloc((size_t)TT * DD * 4);
  float* tw = (float*)alloc((size_t)4 * TT * 4);
  int* cnt  = (int*)alloc(E_N * 4);
  int* list = (int*)alloc((size_t)E_N * TT * 4);
  (void)ws_size; (void)in_sizes; (void)n_in; (void)out_size;

  hipMemsetAsync(cnt, 0, E_N * 4, stream);
  cvt_bf16_kernel<<<TT * DD / 4 / 256, 256, 0, stream>>>(x, Xb);
  router_kernel<<<TT, 256, 0, stream>>>(x, rw, cnt, list, tw);

  // --- gate/up weight transposes: [D][F(S)] -> [F(S)][D] bf16 ---
  tcvt_kernel<<<dim3(DD / 64, FF / 64, E_N), 256, 0, stream>>>(wg, W1, DD, FF);
  tcvt_kernel<<<dim3(DD / 64, FF / 64, E_N), 256, 0, stream>>>(wu, W2, DD, FF);
  tcvt_kernel<<<dim3(DD / 64, FSS / 64, 1), 256, 0, stream>>>(sg, W3, DD, FSS);
  tcvt_kernel<<<dim3(DD / 64, FSS / 64, 1), 256, 0, stream>>>(su, W4, DD, FSS);

  // --- ALL gate+up GEMMs in one launch (z: 16 eG + 1 sG + 16 eU + 1 sU = 34) ---
  gu2_kernel<<<dim3(TT / 128, FSS / 128, 34), 256, 0, stream>>>(
      Xb, W1, W2, W3, W4, Gx, Hx, Gs, Hs, list, cnt);

  // --- h = silu(g)*u ---
  h_kernel<<<(size_t)4 * TT * FF / 8 / 256, 256, 0, stream>>>(Gx, Hx);
  h_kernel<<<(size_t)TT * FSS / 8 / 256, 256, 0, stream>>>(Gs, Hs);

  // --- down weight transposes (reuse W1/W2) ---
  tcvt_kernel<<<dim3(FF / 64, DD / 64, E_N), 256, 0, stream>>>(wd, W1, FF, DD);
  tcvt_kernel<<<dim3(FSS / 64, DD / 64, 1), 256, 0, stream>>>(sd, W2, FSS, DD);

  // --- both down GEMMs in one launch (z: 16 expert + 1 shared) ---
  dn2_kernel<<<dim3(TT / 128, DD / 128, 17), 256, 0, stream>>>(
      Hx, Hs, W1, W2, Y, Ys, list, cnt, tw);

  combine_kernel<<<TT * DD / 4 / 256, 256, 0, stream>>>(Y, Ys, out);
}